// Round 4
// baseline (4015.999 us; speedup 1.0000x reference)
//
#include <hip/hip_runtime.h>

#define NEG_SLOPE 0.01f
#define SCAN_TILE 4096
#define CSHIFT 13               // 8192 rows per coarse bucket (<=49 coarse for N<=400k)
#define FSHIFT 6                // 64 rows per fine bucket
#define FPC (1 << (CSHIFT - FSHIFT))   // 128 fines per coarse
#define WIN 512                 // fine-window in hist_fine/split_fine (covers 4 coarse)
#define TILE_E 2048             // edges per split tile

static inline int cdiv(long long a, long long b) { return (int)((a + b - 1) / b); }

__global__ __launch_bounds__(256) void zero_i32(int* __restrict__ p, int n) {
    int i = blockIdx.x * 256 + threadIdx.x;
    if (i < n) p[i] = 0;
}

// ---- coarse histogram: LDS counters, one merge atomic per (block,bucket) ----
__global__ __launch_bounds__(256) void hist_coarse(const int* __restrict__ rows, int* __restrict__ ccnt, int E) {
    __shared__ int cnt[64];
    int t = threadIdx.x;
    if (t < 64) cnt[t] = 0;
    __syncthreads();
    int base = blockIdx.x * TILE_E;
#pragma unroll
    for (int k = 0; k < TILE_E / 256; k++) {
        int e = base + k * 256 + t;
        if (e < E) atomicAdd(&cnt[rows[e] >> CSHIFT], 1);
    }
    __syncthreads();
    if (t < 64 && cnt[t] > 0) atomicAdd(&ccnt[t], cnt[t]);
}

__global__ void scan_coarse(const int* __restrict__ ccnt, int* __restrict__ cbase,
                            int* __restrict__ cfront, int NBc, int E) {
    if (threadIdx.x == 0 && blockIdx.x == 0) {
        int run = 0;
        for (int b = 0; b < NBc; b++) { cbase[b] = run; cfront[b] = run; run += ccnt[b]; }
        cbase[NBc] = E;
    }
}

// ---- pass A1: LDS multisplit into coarse buckets; dense chunk writes ----
// record: ( (row & 8191) << 19 | col , val )   [13+19 = 32 bits exactly]
__global__ __launch_bounds__(256) void split_coarse(
    const int* __restrict__ rows, const int* __restrict__ cols, const float* __restrict__ vals,
    int* __restrict__ cfront, int2* __restrict__ stg1, int E)
{
    __shared__ int cnt[64], gb[64];
    int t = threadIdx.x;
    if (t < 64) cnt[t] = 0;
    __syncthreads();
    int base = blockIdx.x * TILE_E;
    int myb[8], myrank[8]; int2 mycv[8];
#pragma unroll
    for (int k = 0; k < 8; k++) {
        int e = base + k * 256 + t;
        myb[k] = -1;
        if (e < E) {
            int r = rows[e];
            int b = r >> CSHIFT;
            mycv[k] = make_int2((int)(((unsigned)(r & ((1 << CSHIFT) - 1)) << 19) | (unsigned)cols[e]),
                                __float_as_int(vals[e]));
            myb[k] = b;
            myrank[k] = atomicAdd(&cnt[b], 1);
        }
    }
    __syncthreads();
    if (t < 64 && cnt[t] > 0) gb[t] = atomicAdd(&cfront[t], cnt[t]);
    __syncthreads();
#pragma unroll
    for (int k = 0; k < 8; k++)
        if (myb[k] >= 0) stg1[gb[myb[k]] + myrank[k]] = mycv[k];
}

// ---- fine histogram from coarse-sorted staging (windowed LDS counters) ----
__global__ __launch_bounds__(256) void hist_fine(
    const int2* __restrict__ stg1, const int* __restrict__ cbase_g,
    int* __restrict__ fcnt, int E, int NBc)
{
    __shared__ int cb[65];
    __shared__ int wc[WIN];
    int t = threadIdx.x;
    for (int i = t; i <= NBc; i += 256) cb[i] = cbase_g[i];
    for (int i = t; i < WIN; i += 256) wc[i] = 0;
    __syncthreads();
    int base = blockIdx.x * TILE_E;
    int lo = 0, hi = NBc - 1;
    while (lo < hi) { int m = (lo + hi + 1) >> 1; if (cb[m] <= base) lo = m; else hi = m - 1; }
    int winf = lo * FPC;
#pragma unroll
    for (int k = 0; k < 8; k++) {
        int e = base + k * 256 + t;
        if (e >= E) break;
        int b = lo;
        while (cb[b + 1] <= e) b++;
        unsigned p = (unsigned)stg1[e].x;
        int f = b * FPC + (int)(p >> 19 >> FSHIFT);
        int lf = f - winf;
        if (lf >= 0 && lf < WIN) atomicAdd(&wc[lf], 1);
        else atomicAdd(&fcnt[f], 1);     // robustness fallback (tiny coarse buckets)
    }
    __syncthreads();
    for (int i = t; i < WIN; i += 256)
        if (wc[i] > 0) atomicAdd(&fcnt[winf + i], wc[i]);
}

// ---- scans over fine buckets (NBf <= 6250) ----
__global__ __launch_bounds__(256) void scan1(const int* __restrict__ cnt, int* __restrict__ bsums, int N) {
    __shared__ int sd[256];
    int base = blockIdx.x * SCAN_TILE + threadIdx.x * 16;
    int s = 0;
#pragma unroll
    for (int k = 0; k < 16; k++) { int i = base + k; if (i < N) s += cnt[i]; }
    sd[threadIdx.x] = s; __syncthreads();
    for (int off = 128; off > 0; off >>= 1) {
        if (threadIdx.x < (unsigned)off) sd[threadIdx.x] += sd[threadIdx.x + off];
        __syncthreads();
    }
    if (threadIdx.x == 0) bsums[blockIdx.x] = sd[0];
}

__global__ void scan2(int* __restrict__ bsums, int nb) {
    if (threadIdx.x == 0 && blockIdx.x == 0) {
        int run = 0;
        for (int i = 0; i < nb; i++) { int v = bsums[i]; bsums[i] = run; run += v; }
    }
}

// dual-write: fbase[i] = exclusive scan; cnt_pos rewritten in place as fronts
__global__ __launch_bounds__(256) void scan3(int* __restrict__ cnt_pos, int* __restrict__ fbase,
                                             const int* __restrict__ bsums, int N, int E) {
    __shared__ int sd[256];
    int t = threadIdx.x;
    int base = blockIdx.x * SCAN_TILE + t * 16;
    int v[16]; int s = 0;
#pragma unroll
    for (int k = 0; k < 16; k++) { int i = base + k; v[k] = (i < N) ? cnt_pos[i] : 0; s += v[k]; }
    sd[t] = s; __syncthreads();
    for (int off = 1; off < 256; off <<= 1) {
        int x = (t >= off) ? sd[t - off] : 0;
        __syncthreads();
        sd[t] += x;
        __syncthreads();
    }
    int excl = sd[t] - s + bsums[blockIdx.x];
#pragma unroll
    for (int k = 0; k < 16; k++) {
        int i = base + k;
        if (i < N) { fbase[i] = excl; cnt_pos[i] = excl; excl += v[k]; }
    }
    if (blockIdx.x == 0 && t == 0) fbase[N] = E;
}

// ---- pass A2: split coarse-sorted staging into fine (64-row) buckets ----
// record: ( (row & 63) << 19 | col , val )
__global__ __launch_bounds__(256) void split_fine(
    const int2* __restrict__ stg1, const int* __restrict__ cbase_g,
    int* __restrict__ ffront, int2* __restrict__ stg2, int E, int NBc)
{
    __shared__ int cb[65];
    __shared__ int wc[WIN], wg[WIN];
    int t = threadIdx.x;
    for (int i = t; i <= NBc; i += 256) cb[i] = cbase_g[i];
    for (int i = t; i < WIN; i += 256) wc[i] = 0;
    __syncthreads();
    int base = blockIdx.x * TILE_E;
    int lo = 0, hi = NBc - 1;
    while (lo < hi) { int m = (lo + hi + 1) >> 1; if (cb[m] <= base) lo = m; else hi = m - 1; }
    int winf = lo * FPC;
    int mylf[8], myrank[8]; int2 myp[8];
#pragma unroll
    for (int k = 0; k < 8; k++) {
        int e = base + k * 256 + t;
        mylf[k] = -1;
        if (e < E) {
            int b = lo;
            while (cb[b + 1] <= e) b++;
            int2 cv = stg1[e];
            unsigned p = (unsigned)cv.x;
            int rl13 = (int)(p >> 19);
            int col = (int)(p & 0x7FFFFu);
            int f = b * FPC + (rl13 >> FSHIFT);
            int2 p2 = make_int2((int)(((unsigned)(rl13 & 63) << 19) | (unsigned)col), cv.y);
            int lf = f - winf;
            if (lf >= 0 && lf < WIN) { mylf[k] = lf; myrank[k] = atomicAdd(&wc[lf], 1); myp[k] = p2; }
            else stg2[atomicAdd(&ffront[f], 1)] = p2;   // rare fallback
        }
    }
    __syncthreads();
    for (int i = t; i < WIN; i += 256)
        if (wc[i] > 0) wg[i] = atomicAdd(&ffront[winf + i], wc[i]);
    __syncthreads();
#pragma unroll
    for (int k = 0; k < 8; k++)
        if (mylf[k] >= 0) stg2[wg[mylf[k]] + myrank[k]] = myp[k];
}

// H[n,:] = act(in[n,:]) @ W[0:32,:] + b ;  Z[n,:] = act(in[n,:]) @ W[32:64,:]
template<int COUT, bool LRELU>
__global__ __launch_bounds__(256) void dense_kernel(
    const float* in, const float* __restrict__ W,
    const float* __restrict__ b, float* H,
    float* __restrict__ Z, int N)
{
    int n = blockIdx.x * 256 + threadIdx.x;
    if (n >= N) return;
    const float* row = in + (size_t)n * 32;
    float xv[32];
#pragma unroll
    for (int f = 0; f < 32; f += 4) {
        float4 v = *(const float4*)(row + f);
        xv[f] = v.x; xv[f + 1] = v.y; xv[f + 2] = v.z; xv[f + 3] = v.w;
    }
    if (LRELU) {
#pragma unroll
        for (int f = 0; f < 32; f++) xv[f] = xv[f] > 0.f ? xv[f] : NEG_SLOPE * xv[f];
    }
    float acct[COUT], accb[COUT];
#pragma unroll
    for (int c = 0; c < COUT; c++) { acct[c] = b[c]; accb[c] = 0.f; }
#pragma unroll 4
    for (int f = 0; f < 32; f++) {
        float xf = xv[f];
#pragma unroll
        for (int c = 0; c < COUT; c++) {
            acct[c] = fmaf(xf, W[f * COUT + c], acct[c]);
            accb[c] = fmaf(xf, W[(32 + f) * COUT + c], accb[c]);
        }
    }
    float* hrow = H + (size_t)n * 32;
    float* zrow = Z + (size_t)n * 32;
#pragma unroll
    for (int c = 0; c < COUT; c++) { hrow[c] = acct[c]; zrow[c] = accb[c]; }
}

// ---- gather: one block per 64-row fine bucket, LDS tile + ds_add_f32 ----
__global__ __launch_bounds__(256) void gather32b(
    const int* __restrict__ fbase, const int2* __restrict__ stg2,
    const float* __restrict__ Z, float* __restrict__ H, int N)
{
    __shared__ float tile[64 * 33];
    int b = blockIdx.x, t = threadIdx.x;
    int row0 = b << FSHIFT;
#pragma unroll
    for (int q = 0; q < 2; q++) {
        int j = t + q * 256;
        int i = j >> 3, c = (j & 7) * 4;
        int r = row0 + i;
        if (r < N) {
            float4 v = *(const float4*)(H + (size_t)r * 32 + c);
            tile[i * 33 + c] = v.x; tile[i * 33 + c + 1] = v.y;
            tile[i * 33 + c + 2] = v.z; tile[i * 33 + c + 3] = v.w;
        }
    }
    __syncthreads();
    int s = fbase[b], e = fbase[b + 1];
    int lane = t & 7;
    for (int i = s + (t >> 3); i < e; i += 32) {
        int2 cv = stg2[i];
        unsigned p = (unsigned)cv.x;
        int col = (int)(p & 0x7FFFFu);
        int rl = (int)(p >> 19);
        float v = __int_as_float(cv.y);
        float4 z = *(const float4*)(Z + (size_t)col * 32 + lane * 4);
        atomicAdd(&tile[rl * 33 + lane * 4 + 0], v * z.x);
        atomicAdd(&tile[rl * 33 + lane * 4 + 1], v * z.y);
        atomicAdd(&tile[rl * 33 + lane * 4 + 2], v * z.z);
        atomicAdd(&tile[rl * 33 + lane * 4 + 3], v * z.w);
    }
    __syncthreads();
#pragma unroll
    for (int q = 0; q < 2; q++) {
        int j = t + q * 256;
        int i = j >> 3, c = (j & 7) * 4;
        int r = row0 + i;
        if (r < N) {
            float4 v;
            v.x = tile[i * 33 + c]; v.y = tile[i * 33 + c + 1];
            v.z = tile[i * 33 + c + 2]; v.w = tile[i * 33 + c + 3];
            *(float4*)(H + (size_t)r * 32 + c) = v;
        }
    }
}

__global__ __launch_bounds__(256) void gather10b(
    const int* __restrict__ fbase, const int2* __restrict__ stg2,
    const float* __restrict__ Z, float* __restrict__ H, int N)
{
    __shared__ float tile[64 * 11];
    int b = blockIdx.x, t = threadIdx.x;
    int row0 = b << FSHIFT;
    for (int j = t; j < 640; j += 256) {
        int i = j / 10, c = j % 10;
        int r = row0 + i;
        if (r < N) tile[i * 11 + c] = H[(size_t)r * 32 + c];
    }
    __syncthreads();
    int s = fbase[b], e = fbase[b + 1];
    int lane = t & 7;
    for (int i = s + (t >> 3); i < e; i += 32) {
        if (lane < 5) {
            int2 cv = stg2[i];
            unsigned p = (unsigned)cv.x;
            int col = (int)(p & 0x7FFFFu);
            int rl = (int)(p >> 19);
            float v = __int_as_float(cv.y);
            float2 z = *(const float2*)(Z + (size_t)col * 32 + lane * 2);
            atomicAdd(&tile[rl * 11 + lane * 2 + 0], v * z.x);
            atomicAdd(&tile[rl * 11 + lane * 2 + 1], v * z.y);
        }
    }
    __syncthreads();
    for (int j = t; j < 640; j += 256) {
        int i = j / 10, c = j % 10;
        int r = row0 + i;
        if (r < N) H[(size_t)r * 32 + c] = tile[i * 11 + c];
    }
}

// one block per graph; batch is sorted -> binary search node range, no atomics
__global__ __launch_bounds__(256) void pool_graph(
    const float* __restrict__ H, const int* __restrict__ batch,
    float* __restrict__ pool, int N, int dimoff)
{
    int g = blockIdx.x;
    int lo = 0, hi = N;
    while (lo < hi) { int mid = (lo + hi) >> 1; if (batch[mid] < g) lo = mid + 1; else hi = mid; }
    int start = lo;
    lo = start; hi = N;
    while (lo < hi) { int mid = (lo + hi) >> 1; if (batch[mid] < g + 1) lo = mid + 1; else hi = mid; }
    int end = lo;
    int t = threadIdx.x, f = t & 15, chain = t >> 4;
    __shared__ float sd[256];
    float acc = 0.f;
    if (f < 10) {
        for (int i = start + chain; i < end; i += 16) acc += H[(size_t)i * 32 + f];
    }
    sd[t] = acc; __syncthreads();
    if (chain == 0 && f < 10) {
        float s = 0.f;
#pragma unroll
        for (int k = 0; k < 16; k++) s += sd[k * 16 + f];
        int c = end - start;
        float inv = 1.f / (float)(c > 1 ? c : 1);
        pool[(size_t)g * 30 + dimoff + f] = s * inv;
    }
}

__global__ __launch_bounds__(256) void final_kernel(
    const float* __restrict__ pool, const float* __restrict__ Wf,
    const float* __restrict__ bfv, float* __restrict__ out, int G)
{
    int g = blockIdx.x * 256 + threadIdx.x;
    if (g >= G) return;
    float m[30];
#pragma unroll
    for (int j = 0; j < 30; j++) m[j] = pool[(size_t)g * 30 + j];
    float lg[10];
#pragma unroll
    for (int o = 0; o < 10; o++) {
        float a = bfv[o];
#pragma unroll
        for (int j = 0; j < 30; j++) a = fmaf(m[j], Wf[j * 10 + o], a);
        lg[o] = a;
    }
    float mx = lg[0];
#pragma unroll
    for (int o = 1; o < 10; o++) mx = fmaxf(mx, lg[o]);
    float s = 0.f;
#pragma unroll
    for (int o = 0; o < 10; o++) { lg[o] = __expf(lg[o] - mx); s += lg[o]; }
    float invs = 1.f / s;
#pragma unroll
    for (int o = 0; o < 10; o++) out[(size_t)g * 10 + o] = lg[o] * invs;
}

extern "C" void kernel_launch(void* const* d_in, const int* in_sizes, int n_in,
                              void* d_out, int out_size, void* d_ws, size_t ws_size,
                              hipStream_t stream)
{
    (void)n_in; (void)ws_size;
    const float* x[3]    = {(const float*)d_in[0], (const float*)d_in[1], (const float*)d_in[2]};
    const float* vals[3] = {(const float*)d_in[3], (const float*)d_in[4], (const float*)d_in[5]};
    const int* rows[3]   = {(const int*)d_in[6], (const int*)d_in[8], (const int*)d_in[10]};
    const int* cols[3]   = {(const int*)d_in[7], (const int*)d_in[9], (const int*)d_in[11]};
    const int* batch[3]  = {(const int*)d_in[12], (const int*)d_in[13], (const int*)d_in[14]};
    const float* W1[3] = {(const float*)d_in[16], (const float*)d_in[22], (const float*)d_in[28]};
    const float* b1[3] = {(const float*)d_in[17], (const float*)d_in[23], (const float*)d_in[29]};
    const float* W2[3] = {(const float*)d_in[18], (const float*)d_in[24], (const float*)d_in[30]};
    const float* b2[3] = {(const float*)d_in[19], (const float*)d_in[25], (const float*)d_in[31]};
    const float* W3[3] = {(const float*)d_in[20], (const float*)d_in[26], (const float*)d_in[32]};
    const float* b3[3] = {(const float*)d_in[21], (const float*)d_in[27], (const float*)d_in[33]};
    const float* Wf  = (const float*)d_in[34];
    const float* bfv = (const float*)d_in[35];
    float* out = (float*)d_out;

    int N[3] = {in_sizes[0] / 32, in_sizes[1] / 32, in_sizes[2] / 32};
    int E[3] = {in_sizes[3], in_sizes[4], in_sizes[5]};
    int G = out_size / 10;
    int maxN = N[0]; if (N[1] > maxN) maxN = N[1]; if (N[2] > maxN) maxN = N[2];
    int maxE = E[0]; if (E[1] > maxE) maxE = E[1]; if (E[2] > maxE) maxE = E[2];
    int maxNBf = cdiv(maxN, 1 << FSHIFT);

    float* bufA   = (float*)d_ws;
    float* bufZ   = bufA + (size_t)maxN * 32;
    float* pool   = bufZ + (size_t)maxN * 32;
    int2*  stg1   = (int2*)(pool + (size_t)G * 30);
    int2*  stg2   = stg1 + maxE;
    int*   fcnt   = (int*)(stg2 + maxE);       // becomes ffront after scan3
    int*   fbase  = fcnt + maxNBf;
    int*   ccnt   = fbase + (maxNBf + 1);
    int*   cbase  = ccnt + 64;
    int*   cfront = cbase + 65;
    int*   bsums  = cfront + 64;

    for (int d = 0; d < 3; d++) {
        int n = N[d], e = E[d];
        int NBc = cdiv(n, 1 << CSHIFT);
        int NBf = cdiv(n, 1 << FSHIFT);
        int ntile = cdiv(e, TILE_E);
        int nbf_blocks = cdiv(NBf, SCAN_TILE);

        // --- build fine-bucketed edge list (two-level LDS multisplit) ---
        zero_i32<<<1, 256, 0, stream>>>(ccnt, 64);
        hist_coarse<<<ntile, 256, 0, stream>>>(rows[d], ccnt, e);
        scan_coarse<<<1, 64, 0, stream>>>(ccnt, cbase, cfront, NBc, e);
        split_coarse<<<ntile, 256, 0, stream>>>(rows[d], cols[d], vals[d], cfront, stg1, e);
        zero_i32<<<cdiv(NBf, 256), 256, 0, stream>>>(fcnt, NBf);
        hist_fine<<<ntile, 256, 0, stream>>>(stg1, cbase, fcnt, e, NBc);
        scan1<<<nbf_blocks, 256, 0, stream>>>(fcnt, bsums, NBf);
        scan2<<<1, 64, 0, stream>>>(bsums, nbf_blocks);
        scan3<<<nbf_blocks, 256, 0, stream>>>(fcnt, fbase, bsums, NBf, e);
        split_fine<<<ntile, 256, 0, stream>>>(stg1, cbase, fcnt, stg2, e, NBc);

        // --- 3 layers: dense transform + bucketed LDS gather ---
        dense_kernel<32, false><<<cdiv(n, 256), 256, 0, stream>>>(x[d], W1[d], b1[d], bufA, bufZ, n);
        gather32b<<<NBf, 256, 0, stream>>>(fbase, stg2, bufZ, bufA, n);
        dense_kernel<32, true><<<cdiv(n, 256), 256, 0, stream>>>(bufA, W2[d], b2[d], bufA, bufZ, n);
        gather32b<<<NBf, 256, 0, stream>>>(fbase, stg2, bufZ, bufA, n);
        dense_kernel<10, true><<<cdiv(n, 256), 256, 0, stream>>>(bufA, W3[d], b3[d], bufA, bufZ, n);
        gather10b<<<NBf, 256, 0, stream>>>(fbase, stg2, bufZ, bufA, n);
        pool_graph<<<G, 256, 0, stream>>>(bufA, batch[d], pool, n, d * 10);
    }
    final_kernel<<<cdiv(G, 256), 256, 0, stream>>>(pool, Wf, bfv, out, G);
}

// Round 5
// 2355.541 us; speedup vs baseline: 1.7049x; 1.7049x over previous
//
#include <hip/hip_runtime.h>

#define NEG_SLOPE 0.01f
#define SCAN_TILE 4096
#define CSHIFT 13               // 8192 rows per coarse bucket (<=49 coarse for N<=400k)
#define TILE_E 2048             // edges per split tile

static inline int cdiv(long long a, long long b) { return (int)((a + b - 1) / b); }

__global__ __launch_bounds__(256) void zero_i32(int* __restrict__ p, int n) {
    int i = blockIdx.x * 256 + threadIdx.x;
    if (i < n) p[i] = 0;
}

__global__ __launch_bounds__(256) void hist_rows(const int* __restrict__ rows, int* __restrict__ cnt, int E) {
    int e = blockIdx.x * 256 + threadIdx.x;
    if (e < E) atomicAdd(&cnt[rows[e]], 1);
}

// ---- scans over row counts (N-sized) ----
__global__ __launch_bounds__(256) void scan1(const int* __restrict__ cnt, int* __restrict__ bsums, int N) {
    __shared__ int sd[256];
    int base = blockIdx.x * SCAN_TILE + threadIdx.x * 16;
    int s = 0;
#pragma unroll
    for (int k = 0; k < 16; k++) { int i = base + k; if (i < N) s += cnt[i]; }
    sd[threadIdx.x] = s; __syncthreads();
    for (int off = 128; off > 0; off >>= 1) {
        if (threadIdx.x < (unsigned)off) sd[threadIdx.x] += sd[threadIdx.x + off];
        __syncthreads();
    }
    if (threadIdx.x == 0) bsums[blockIdx.x] = sd[0];
}

__global__ void scan2(int* __restrict__ bsums, int nb) {
    if (threadIdx.x == 0 && blockIdx.x == 0) {
        int run = 0;
        for (int i = 0; i < nb; i++) { int v = bsums[i]; bsums[i] = run; run += v; }
    }
}

// dual-write: rowptr[i] = exclusive scan; cnt_pos rewritten in place as fronts
__global__ __launch_bounds__(256) void scan3(int* __restrict__ cnt_pos, int* __restrict__ rowptr,
                                             const int* __restrict__ bsums, int N, int E) {
    __shared__ int sd[256];
    int t = threadIdx.x;
    int base = blockIdx.x * SCAN_TILE + t * 16;
    int v[16]; int s = 0;
#pragma unroll
    for (int k = 0; k < 16; k++) { int i = base + k; v[k] = (i < N) ? cnt_pos[i] : 0; s += v[k]; }
    sd[t] = s; __syncthreads();
    for (int off = 1; off < 256; off <<= 1) {
        int x = (t >= off) ? sd[t - off] : 0;
        __syncthreads();
        sd[t] += x;
        __syncthreads();
    }
    int excl = sd[t] - s + bsums[blockIdx.x];
#pragma unroll
    for (int k = 0; k < 16; k++) {
        int i = base + k;
        if (i < N) { rowptr[i] = excl; cnt_pos[i] = excl; excl += v[k]; }
    }
    if (blockIdx.x == 0 && t == 0) rowptr[N] = E;
}

// ---- coarse histogram: LDS counters, one merge atomic per (block,bucket) ----
__global__ __launch_bounds__(256) void hist_coarse(const int* __restrict__ rows, int* __restrict__ ccnt, int E) {
    __shared__ int cnt[64];
    int t = threadIdx.x;
    if (t < 64) cnt[t] = 0;
    __syncthreads();
    int base = blockIdx.x * TILE_E;
#pragma unroll
    for (int k = 0; k < TILE_E / 256; k++) {
        int e = base + k * 256 + t;
        if (e < E) atomicAdd(&cnt[rows[e] >> CSHIFT], 1);
    }
    __syncthreads();
    if (t < 64 && cnt[t] > 0) atomicAdd(&ccnt[t], cnt[t]);
}

__global__ void scan_coarse(const int* __restrict__ ccnt, int* __restrict__ cbase,
                            int* __restrict__ cfront, int NBc, int E) {
    if (threadIdx.x == 0 && blockIdx.x == 0) {
        int run = 0;
        for (int b = 0; b < NBc; b++) { cbase[b] = run; cfront[b] = run; run += ccnt[b]; }
        cbase[NBc] = E;
    }
}

// ---- pass A: LDS multisplit into coarse buckets; dense chunk writes ----
// record: ( (row & 8191) << 19 | col , val )   [13+19 = 32 bits exactly]
__global__ __launch_bounds__(256) void split_coarse(
    const int* __restrict__ rows, const int* __restrict__ cols, const float* __restrict__ vals,
    int* __restrict__ cfront, int2* __restrict__ stg1, int E)
{
    __shared__ int cnt[64], gb[64];
    int t = threadIdx.x;
    if (t < 64) cnt[t] = 0;
    __syncthreads();
    int base = blockIdx.x * TILE_E;
    int myb[8], myrank[8]; int2 mycv[8];
#pragma unroll
    for (int k = 0; k < 8; k++) {
        int e = base + k * 256 + t;
        myb[k] = -1;
        if (e < E) {
            int r = rows[e];
            int b = r >> CSHIFT;
            mycv[k] = make_int2((int)(((unsigned)(r & ((1 << CSHIFT) - 1)) << 19) | (unsigned)cols[e]),
                                __float_as_int(vals[e]));
            myb[k] = b;
            myrank[k] = atomicAdd(&cnt[b], 1);
        }
    }
    __syncthreads();
    if (t < 64 && cnt[t] > 0) gb[t] = atomicAdd(&cfront[t], cnt[t]);
    __syncthreads();
#pragma unroll
    for (int k = 0; k < 8; k++)
        if (myb[k] >= 0) stg1[gb[myb[k]] + myrank[k]] = mycv[k];
}

// ---- pass B: coarse-sorted staging -> exact CSR position (window-local scatter) ----
__global__ __launch_bounds__(256) void csr_fill2(
    const int2* __restrict__ stg1, const int* __restrict__ cbase_g,
    int* __restrict__ pos, int2* __restrict__ ecv, int E, int NBc)
{
    __shared__ int cb[66];
    int t = threadIdx.x;
    for (int i = t; i <= NBc; i += 256) cb[i] = cbase_g[i];
    __syncthreads();
    int base = blockIdx.x * TILE_E;
    if (base >= E) return;
    int lo = 0, hi = NBc - 1;
    while (lo < hi) { int m = (lo + hi + 1) >> 1; if (cb[m] <= base) lo = m; else hi = m - 1; }
#pragma unroll
    for (int k = 0; k < 8; k++) {
        int e = base + k * 256 + t;
        if (e < E) {
            int b = lo;
            while (cb[b + 1] <= e) b++;
            int2 cv = stg1[e];
            unsigned p = (unsigned)cv.x;
            int row = (b << CSHIFT) + (int)(p >> 19);
            int col = (int)(p & 0x7FFFFu);
            int q = atomicAdd(&pos[row], 1);
            ecv[q] = make_int2(col, cv.y);
        }
    }
}

// H[n,:] = act(in[n,:]) @ W[0:32,:] + b ;  Z[n,:] = act(in[n,:]) @ W[32:64,:]
// in/H may alias (in-place): each thread reads its row fully before writing.
template<int COUT, bool LRELU>
__global__ __launch_bounds__(256) void dense_kernel(
    const float* in, const float* __restrict__ W,
    const float* __restrict__ b, float* H,
    float* __restrict__ Z, int N)
{
    int n = blockIdx.x * 256 + threadIdx.x;
    if (n >= N) return;
    const float* row = in + (size_t)n * 32;
    float xv[32];
#pragma unroll
    for (int f = 0; f < 32; f += 4) {
        float4 v = *(const float4*)(row + f);
        xv[f] = v.x; xv[f + 1] = v.y; xv[f + 2] = v.z; xv[f + 3] = v.w;
    }
    if (LRELU) {
#pragma unroll
        for (int f = 0; f < 32; f++) xv[f] = xv[f] > 0.f ? xv[f] : NEG_SLOPE * xv[f];
    }
    float acct[COUT], accb[COUT];
#pragma unroll
    for (int c = 0; c < COUT; c++) { acct[c] = b[c]; accb[c] = 0.f; }
#pragma unroll 4
    for (int f = 0; f < 32; f++) {
        float xf = xv[f];
#pragma unroll
        for (int c = 0; c < COUT; c++) {
            acct[c] = fmaf(xf, W[f * COUT + c], acct[c]);
            accb[c] = fmaf(xf, W[(32 + f) * COUT + c], accb[c]);
        }
    }
    float* hrow = H + (size_t)n * 32;
    float* zrow = Z + (size_t)n * 32;
#pragma unroll
    for (int c = 0; c < COUT; c++) { hrow[c] = acct[c]; zrow[c] = accb[c]; }
}

// conflict-free CSR gather: H[r,:] += sum_e val[e] * Z[col[e],:]  (C=32, 8 lanes x float4)
__global__ __launch_bounds__(256) void gather32(
    const int* __restrict__ rowptr, const int2* __restrict__ ecv,
    const float* __restrict__ Z, float* __restrict__ H, int N)
{
    int tid = blockIdx.x * 256 + threadIdx.x;
    int row = tid >> 3, lane = tid & 7;
    if (row >= N) return;
    int s = rowptr[row], e = rowptr[row + 1];
    float ax = 0.f, ay = 0.f, az = 0.f, aw = 0.f;
    for (int i = s; i < e; i++) {
        int2 cv = ecv[i];
        float v = __int_as_float(cv.y);
        float4 z = *(const float4*)(Z + (size_t)cv.x * 32 + lane * 4);
        ax = fmaf(v, z.x, ax); ay = fmaf(v, z.y, ay);
        az = fmaf(v, z.z, az); aw = fmaf(v, z.w, aw);
    }
    float4* hp = (float4*)(H + (size_t)row * 32 + lane * 4);
    float4 h = *hp;
    h.x += ax; h.y += ay; h.z += az; h.w += aw;
    *hp = h;
}

// C=10: 8 lanes per row, lanes 0..4 each handle a float2
__global__ __launch_bounds__(256) void gather10(
    const int* __restrict__ rowptr, const int2* __restrict__ ecv,
    const float* __restrict__ Z, float* __restrict__ H, int N)
{
    int tid = blockIdx.x * 256 + threadIdx.x;
    int row = tid >> 3, lane = tid & 7;
    if (row >= N || lane >= 5) return;
    int s = rowptr[row], e = rowptr[row + 1];
    float ax = 0.f, ay = 0.f;
    for (int i = s; i < e; i++) {
        int2 cv = ecv[i];
        float v = __int_as_float(cv.y);
        float2 z = *(const float2*)(Z + (size_t)cv.x * 32 + lane * 2);
        ax = fmaf(v, z.x, ax); ay = fmaf(v, z.y, ay);
    }
    float* hp = H + (size_t)row * 32 + lane * 2;
    hp[0] += ax; hp[1] += ay;
}

// one block per graph; batch is sorted -> binary search node range, no atomics
__global__ __launch_bounds__(256) void pool_graph(
    const float* __restrict__ H, const int* __restrict__ batch,
    float* __restrict__ pool, int N, int dimoff)
{
    int g = blockIdx.x;
    int lo = 0, hi = N;
    while (lo < hi) { int mid = (lo + hi) >> 1; if (batch[mid] < g) lo = mid + 1; else hi = mid; }
    int start = lo;
    lo = start; hi = N;
    while (lo < hi) { int mid = (lo + hi) >> 1; if (batch[mid] < g + 1) lo = mid + 1; else hi = mid; }
    int end = lo;
    int t = threadIdx.x, f = t & 15, chain = t >> 4;
    __shared__ float sd[256];
    float acc = 0.f;
    if (f < 10) {
        for (int i = start + chain; i < end; i += 16) acc += H[(size_t)i * 32 + f];
    }
    sd[t] = acc; __syncthreads();
    if (chain == 0 && f < 10) {
        float s = 0.f;
#pragma unroll
        for (int k = 0; k < 16; k++) s += sd[k * 16 + f];
        int c = end - start;
        float inv = 1.f / (float)(c > 1 ? c : 1);
        pool[(size_t)g * 30 + dimoff + f] = s * inv;
    }
}

__global__ __launch_bounds__(256) void final_kernel(
    const float* __restrict__ pool, const float* __restrict__ Wf,
    const float* __restrict__ bfv, float* __restrict__ out, int G)
{
    int g = blockIdx.x * 256 + threadIdx.x;
    if (g >= G) return;
    float m[30];
#pragma unroll
    for (int j = 0; j < 30; j++) m[j] = pool[(size_t)g * 30 + j];
    float lg[10];
#pragma unroll
    for (int o = 0; o < 10; o++) {
        float a = bfv[o];
#pragma unroll
        for (int j = 0; j < 30; j++) a = fmaf(m[j], Wf[j * 10 + o], a);
        lg[o] = a;
    }
    float mx = lg[0];
#pragma unroll
    for (int o = 1; o < 10; o++) mx = fmaxf(mx, lg[o]);
    float s = 0.f;
#pragma unroll
    for (int o = 0; o < 10; o++) { lg[o] = __expf(lg[o] - mx); s += lg[o]; }
    float invs = 1.f / s;
#pragma unroll
    for (int o = 0; o < 10; o++) out[(size_t)g * 10 + o] = lg[o] * invs;
}

extern "C" void kernel_launch(void* const* d_in, const int* in_sizes, int n_in,
                              void* d_out, int out_size, void* d_ws, size_t ws_size,
                              hipStream_t stream)
{
    (void)n_in; (void)ws_size;
    const float* x[3]    = {(const float*)d_in[0], (const float*)d_in[1], (const float*)d_in[2]};
    const float* vals[3] = {(const float*)d_in[3], (const float*)d_in[4], (const float*)d_in[5]};
    const int* rows[3]   = {(const int*)d_in[6], (const int*)d_in[8], (const int*)d_in[10]};
    const int* cols[3]   = {(const int*)d_in[7], (const int*)d_in[9], (const int*)d_in[11]};
    const int* batch[3]  = {(const int*)d_in[12], (const int*)d_in[13], (const int*)d_in[14]};
    const float* W1[3] = {(const float*)d_in[16], (const float*)d_in[22], (const float*)d_in[28]};
    const float* b1[3] = {(const float*)d_in[17], (const float*)d_in[23], (const float*)d_in[29]};
    const float* W2[3] = {(const float*)d_in[18], (const float*)d_in[24], (const float*)d_in[30]};
    const float* b2[3] = {(const float*)d_in[19], (const float*)d_in[25], (const float*)d_in[31]};
    const float* W3[3] = {(const float*)d_in[20], (const float*)d_in[26], (const float*)d_in[32]};
    const float* b3[3] = {(const float*)d_in[21], (const float*)d_in[27], (const float*)d_in[33]};
    const float* Wf  = (const float*)d_in[34];
    const float* bfv = (const float*)d_in[35];
    float* out = (float*)d_out;

    int N[3] = {in_sizes[0] / 32, in_sizes[1] / 32, in_sizes[2] / 32};
    int E[3] = {in_sizes[3], in_sizes[4], in_sizes[5]};
    int G = out_size / 10;
    int maxN = N[0]; if (N[1] > maxN) maxN = N[1]; if (N[2] > maxN) maxN = N[2];
    int maxE = E[0]; if (E[1] > maxE) maxE = E[1]; if (E[2] > maxE) maxE = E[2];

    float* bufA   = (float*)d_ws;
    float* bufZ   = bufA + (size_t)maxN * 32;
    float* pool   = bufZ + (size_t)maxN * 32;
    int2*  ecv    = (int2*)(pool + (size_t)G * 30 + 2);   // +2 for int2 alignment
    int2*  stg1   = ecv + maxE;
    int*   rowptr = (int*)(stg1 + maxE);
    int*   pos    = rowptr + (maxN + 1);
    int*   ccnt   = pos + maxN;
    int*   cbase  = ccnt + 64;
    int*   cfront = cbase + 66;
    int*   bsums  = cfront + 64;

    for (int d = 0; d < 3; d++) {
        int n = N[d], e = E[d];
        int nb = cdiv(n, SCAN_TILE);
        int NBc = cdiv(n, 1 << CSHIFT);
        int ntile = cdiv(e, TILE_E);

        // --- row histogram + rowptr/pos fronts ---
        zero_i32<<<cdiv(n, 256), 256, 0, stream>>>(pos, n);
        hist_rows<<<cdiv(e, 256), 256, 0, stream>>>(rows[d], pos, e);
        scan1<<<nb, 256, 0, stream>>>(pos, bsums, n);
        scan2<<<1, 64, 0, stream>>>(bsums, nb);
        scan3<<<nb, 256, 0, stream>>>(pos, rowptr, bsums, n, e);
        // --- coarse-bucket staging (dense writes) then window-local CSR fill ---
        zero_i32<<<1, 256, 0, stream>>>(ccnt, 64);
        hist_coarse<<<ntile, 256, 0, stream>>>(rows[d], ccnt, e);
        scan_coarse<<<1, 64, 0, stream>>>(ccnt, cbase, cfront, NBc, e);
        split_coarse<<<ntile, 256, 0, stream>>>(rows[d], cols[d], vals[d], cfront, stg1, e);
        csr_fill2<<<ntile, 256, 0, stream>>>(stg1, cbase, pos, ecv, e, NBc);

        // --- 3 layers, conflict-free CSR gathers (round-2 structure) ---
        dense_kernel<32, false><<<cdiv(n, 256), 256, 0, stream>>>(x[d], W1[d], b1[d], bufA, bufZ, n);
        gather32<<<cdiv((long long)n * 8, 256), 256, 0, stream>>>(rowptr, ecv, bufZ, bufA, n);
        dense_kernel<32, true><<<cdiv(n, 256), 256, 0, stream>>>(bufA, W2[d], b2[d], bufA, bufZ, n);
        gather32<<<cdiv((long long)n * 8, 256), 256, 0, stream>>>(rowptr, ecv, bufZ, bufA, n);
        dense_kernel<10, true><<<cdiv(n, 256), 256, 0, stream>>>(bufA, W3[d], b3[d], bufA, bufZ, n);
        gather10<<<cdiv((long long)n * 8, 256), 256, 0, stream>>>(rowptr, ecv, bufZ, bufA, n);
        pool_graph<<<G, 256, 0, stream>>>(bufA, batch[d], pool, n, d * 10);
    }
    final_kernel<<<cdiv(G, 256), 256, 0, stream>>>(pool, Wf, bfv, out, G);
}

// Round 6
// 1837.285 us; speedup vs baseline: 2.1858x; 1.2821x over previous
//
#include <hip/hip_runtime.h>

#define NEG_SLOPE 0.01f
#define SCAN_TILE 4096
#define CSHIFT 13               // 8192 rows per coarse bucket (<=49 coarse for N<=400k)
#define MSHIFT 7                // 128 rows per mid bucket
#define MPC (1 << (CSHIFT - MSHIFT))   // 64 mids per coarse
#define MWIN 192                // window of mid-counters per split tile (straddle<=2 coarse)
#define CAP 4096                // max edges per mid bucket in csr_sort LDS
#define TILE_E 2048             // edges per split tile

static inline int cdiv(long long a, long long b) { return (int)((a + b - 1) / b); }

__global__ __launch_bounds__(256) void zero_i32(int* __restrict__ p, int n) {
    int i = blockIdx.x * 256 + threadIdx.x;
    if (i < n) p[i] = 0;
}

__global__ __launch_bounds__(256) void hist_rows(const int* __restrict__ rows, int* __restrict__ cnt, int E) {
    int e = blockIdx.x * 256 + threadIdx.x;
    if (e < E) atomicAdd(&cnt[rows[e]], 1);
}

// ---- scans over row counts (N-sized) -> rowptr ----
__global__ __launch_bounds__(256) void scan1(const int* __restrict__ cnt, int* __restrict__ bsums, int N) {
    __shared__ int sd[256];
    int base = blockIdx.x * SCAN_TILE + threadIdx.x * 16;
    int s = 0;
#pragma unroll
    for (int k = 0; k < 16; k++) { int i = base + k; if (i < N) s += cnt[i]; }
    sd[threadIdx.x] = s; __syncthreads();
    for (int off = 128; off > 0; off >>= 1) {
        if (threadIdx.x < (unsigned)off) sd[threadIdx.x] += sd[threadIdx.x + off];
        __syncthreads();
    }
    if (threadIdx.x == 0) bsums[blockIdx.x] = sd[0];
}

__global__ void scan2(int* __restrict__ bsums, int nb) {
    if (threadIdx.x == 0 && blockIdx.x == 0) {
        int run = 0;
        for (int i = 0; i < nb; i++) { int v = bsums[i]; bsums[i] = run; run += v; }
    }
}

__global__ __launch_bounds__(256) void scan3(const int* __restrict__ cnt, int* __restrict__ rowptr,
                                             const int* __restrict__ bsums, int N, int E) {
    __shared__ int sd[256];
    int t = threadIdx.x;
    int base = blockIdx.x * SCAN_TILE + t * 16;
    int v[16]; int s = 0;
#pragma unroll
    for (int k = 0; k < 16; k++) { int i = base + k; v[k] = (i < N) ? cnt[i] : 0; s += v[k]; }
    sd[t] = s; __syncthreads();
    for (int off = 1; off < 256; off <<= 1) {
        int x = (t >= off) ? sd[t - off] : 0;
        __syncthreads();
        sd[t] += x;
        __syncthreads();
    }
    int excl = sd[t] - s + bsums[blockIdx.x];
#pragma unroll
    for (int k = 0; k < 16; k++) {
        int i = base + k;
        if (i < N) { rowptr[i] = excl; excl += v[k]; }
    }
    if (blockIdx.x == 0 && t == 0) rowptr[N] = E;
}

// ---- coarse histogram: LDS counters, one merge atomic per (block,bucket) ----
__global__ __launch_bounds__(256) void hist_coarse(const int* __restrict__ rows, int* __restrict__ ccnt, int E) {
    __shared__ int cnt[64];
    int t = threadIdx.x;
    if (t < 64) cnt[t] = 0;
    __syncthreads();
    int base = blockIdx.x * TILE_E;
#pragma unroll
    for (int k = 0; k < TILE_E / 256; k++) {
        int e = base + k * 256 + t;
        if (e < E) atomicAdd(&cnt[rows[e] >> CSHIFT], 1);
    }
    __syncthreads();
    if (t < 64 && cnt[t] > 0) atomicAdd(&ccnt[t], cnt[t]);
}

__global__ void scan_coarse(const int* __restrict__ ccnt, int* __restrict__ cbase,
                            int* __restrict__ cfront, int NBc, int E) {
    if (threadIdx.x == 0 && blockIdx.x == 0) {
        int run = 0;
        for (int b = 0; b < NBc; b++) { cbase[b] = run; cfront[b] = run; run += ccnt[b]; }
        cbase[NBc] = E;
    }
}

// ---- pass A: LDS multisplit into coarse buckets; dense chunk writes ----
// record: ( (row & 8191) << 19 | col , val )   [13+19 = 32 bits exactly, col < 2^19]
__global__ __launch_bounds__(256) void split_coarse(
    const int* __restrict__ rows, const int* __restrict__ cols, const float* __restrict__ vals,
    int* __restrict__ cfront, int2* __restrict__ stg1, int E)
{
    __shared__ int cnt[64], gb[64];
    int t = threadIdx.x;
    if (t < 64) cnt[t] = 0;
    __syncthreads();
    int base = blockIdx.x * TILE_E;
    int myb[8], myrank[8]; int2 mycv[8];
#pragma unroll
    for (int k = 0; k < 8; k++) {
        int e = base + k * 256 + t;
        myb[k] = -1;
        if (e < E) {
            int r = rows[e];
            int b = r >> CSHIFT;
            mycv[k] = make_int2((int)(((unsigned)(r & ((1 << CSHIFT) - 1)) << 19) | (unsigned)cols[e]),
                                __float_as_int(vals[e]));
            myb[k] = b;
            myrank[k] = atomicAdd(&cnt[b], 1);
        }
    }
    __syncthreads();
    if (t < 64 && cnt[t] > 0) gb[t] = atomicAdd(&cfront[t], cnt[t]);
    __syncthreads();
#pragma unroll
    for (int k = 0; k < 8; k++)
        if (myb[k] >= 0) stg1[gb[myb[k]] + myrank[k]] = mycv[k];
}

// mid-bucket fronts = rowptr at each 128-row boundary
__global__ __launch_bounds__(256) void init_mfront(const int* __restrict__ rowptr,
                                                   int* __restrict__ mfront, int NBm) {
    int m = blockIdx.x * 256 + threadIdx.x;
    if (m < NBm) mfront[m] = rowptr[m << MSHIFT];
}

// ---- pass B: coarse-sorted staging -> mid (128-row) buckets; windowed LDS ranking ----
__global__ __launch_bounds__(256) void split_mid(
    const int2* __restrict__ stg1, const int* __restrict__ cbase_g,
    int* __restrict__ mfront, int2* __restrict__ stgm, int E, int NBc)
{
    __shared__ int cb[66];
    __shared__ int wc[MWIN], wg[MWIN];
    int t = threadIdx.x;
    for (int i = t; i <= NBc; i += 256) cb[i] = cbase_g[i];
    for (int i = t; i < MWIN; i += 256) wc[i] = 0;
    __syncthreads();
    int base = blockIdx.x * TILE_E;
    if (base >= E) return;
    int lo = 0, hi = NBc - 1;
    while (lo < hi) { int m = (lo + hi + 1) >> 1; if (cb[m] <= base) lo = m; else hi = m - 1; }
    int winm = lo * MPC;
    int mylf[8], myrank[8]; int2 myp[8];
#pragma unroll
    for (int k = 0; k < 8; k++) {
        int e = base + k * 256 + t;
        mylf[k] = -1;
        if (e < E) {
            int b = lo;
            while (cb[b + 1] <= e) b++;
            int2 cv = stg1[e];
            int m = (b << (CSHIFT - MSHIFT)) + (int)(((unsigned)cv.x >> 19) >> MSHIFT);
            int lf = m - winm;
            if (lf >= 0 && lf < MWIN) { mylf[k] = lf; myrank[k] = atomicAdd(&wc[lf], 1); myp[k] = cv; }
            else stgm[atomicAdd(&mfront[m], 1)] = cv;   // rare fallback
        }
    }
    __syncthreads();
    for (int i = t; i < MWIN; i += 256)
        if (wc[i] > 0) wg[i] = atomicAdd(&mfront[winm + i], wc[i]);
    __syncthreads();
#pragma unroll
    for (int k = 0; k < 8; k++)
        if (mylf[k] >= 0) stgm[wg[mylf[k]] + myrank[k]] = myp[k];
}

// ---- pass C: one block per mid bucket; LDS counting sort to exact CSR; sequential writes ----
__global__ __launch_bounds__(256) void csr_sort(
    const int2* __restrict__ stgm, const int* __restrict__ rowptr,
    int2* __restrict__ ecv, int N)
{
    __shared__ int2 buf[CAP];
    __shared__ int front[1 << MSHIFT];
    int mb = blockIdx.x, t = threadIdx.x;
    int row0 = mb << MSHIFT;
    int nrows = N - row0; if (nrows > (1 << MSHIFT)) nrows = 1 << MSHIFT;
    for (int j = t; j < nrows; j += 256) front[j] = rowptr[row0 + j];
    __syncthreads();
    int s = rowptr[row0], eend = rowptr[row0 + nrows];
    for (int i = s + t; i < eend; i += 256) {
        int2 cv = stgm[i];
        unsigned p = (unsigned)cv.x;
        int rl = ((int)(p >> 19)) & ((1 << MSHIFT) - 1);
        int2 rec = make_int2((int)(p & 0x7FFFFu), cv.y);
        int pos = atomicAdd(&front[rl], 1);
        int l = pos - s;
        if (l < CAP) buf[l] = rec;
        else ecv[pos] = rec;                 // overflow fallback (statistically never)
    }
    __syncthreads();
    int cnt = eend - s; if (cnt > CAP) cnt = CAP;
    for (int l = t; l < cnt; l += 256) ecv[s + l] = buf[l];
}

// H[n,:] = act(in[n,:]) @ W[0:32,:] + b ;  Z[n,:] = act(in[n,:]) @ W[32:64,:]
template<int COUT, bool LRELU>
__global__ __launch_bounds__(256) void dense_kernel(
    const float* in, const float* __restrict__ W,
    const float* __restrict__ b, float* H,
    float* __restrict__ Z, int N)
{
    int n = blockIdx.x * 256 + threadIdx.x;
    if (n >= N) return;
    const float* row = in + (size_t)n * 32;
    float xv[32];
#pragma unroll
    for (int f = 0; f < 32; f += 4) {
        float4 v = *(const float4*)(row + f);
        xv[f] = v.x; xv[f + 1] = v.y; xv[f + 2] = v.z; xv[f + 3] = v.w;
    }
    if (LRELU) {
#pragma unroll
        for (int f = 0; f < 32; f++) xv[f] = xv[f] > 0.f ? xv[f] : NEG_SLOPE * xv[f];
    }
    float acct[COUT], accb[COUT];
#pragma unroll
    for (int c = 0; c < COUT; c++) { acct[c] = b[c]; accb[c] = 0.f; }
#pragma unroll 4
    for (int f = 0; f < 32; f++) {
        float xf = xv[f];
#pragma unroll
        for (int c = 0; c < COUT; c++) {
            acct[c] = fmaf(xf, W[f * COUT + c], acct[c]);
            accb[c] = fmaf(xf, W[(32 + f) * COUT + c], accb[c]);
        }
    }
    float* hrow = H + (size_t)n * 32;
    float* zrow = Z + (size_t)n * 32;
#pragma unroll
    for (int c = 0; c < COUT; c++) { hrow[c] = acct[c]; zrow[c] = accb[c]; }
}

// CSR gather, 2 interleaved row-chains per thread for MLP (C=32, 8 lanes x float4)
__global__ __launch_bounds__(256) void gather32(
    const int* __restrict__ rowptr, const int2* __restrict__ ecv,
    const float* __restrict__ Z, float* __restrict__ H, int N)
{
    int tid = blockIdx.x * 256 + threadIdx.x;
    int pr = tid >> 3, lane = tid & 7;
    int r0 = pr * 2, r1 = r0 + 1;
    if (r0 >= N) return;
    int s0 = rowptr[r0], e0 = rowptr[r0 + 1];
    int s1 = 0, e1 = 0;
    if (r1 < N) { s1 = rowptr[r1]; e1 = rowptr[r1 + 1]; }
    float ax0 = 0.f, ay0 = 0.f, az0 = 0.f, aw0 = 0.f;
    float ax1 = 0.f, ay1 = 0.f, az1 = 0.f, aw1 = 0.f;
    int i0 = s0, i1 = s1;
    while (i0 < e0 && i1 < e1) {
        int2 c0 = ecv[i0]; int2 c1 = ecv[i1];
        float4 z0 = *(const float4*)(Z + (size_t)c0.x * 32 + lane * 4);
        float4 z1 = *(const float4*)(Z + (size_t)c1.x * 32 + lane * 4);
        float v0 = __int_as_float(c0.y), v1 = __int_as_float(c1.y);
        ax0 = fmaf(v0, z0.x, ax0); ay0 = fmaf(v0, z0.y, ay0);
        az0 = fmaf(v0, z0.z, az0); aw0 = fmaf(v0, z0.w, aw0);
        ax1 = fmaf(v1, z1.x, ax1); ay1 = fmaf(v1, z1.y, ay1);
        az1 = fmaf(v1, z1.z, az1); aw1 = fmaf(v1, z1.w, aw1);
        i0++; i1++;
    }
    for (; i0 < e0; i0++) {
        int2 c0 = ecv[i0];
        float4 z0 = *(const float4*)(Z + (size_t)c0.x * 32 + lane * 4);
        float v0 = __int_as_float(c0.y);
        ax0 = fmaf(v0, z0.x, ax0); ay0 = fmaf(v0, z0.y, ay0);
        az0 = fmaf(v0, z0.z, az0); aw0 = fmaf(v0, z0.w, aw0);
    }
    for (; i1 < e1; i1++) {
        int2 c1 = ecv[i1];
        float4 z1 = *(const float4*)(Z + (size_t)c1.x * 32 + lane * 4);
        float v1 = __int_as_float(c1.y);
        ax1 = fmaf(v1, z1.x, ax1); ay1 = fmaf(v1, z1.y, ay1);
        az1 = fmaf(v1, z1.z, az1); aw1 = fmaf(v1, z1.w, aw1);
    }
    float4* hp0 = (float4*)(H + (size_t)r0 * 32 + lane * 4);
    float4 h0 = *hp0;
    h0.x += ax0; h0.y += ay0; h0.z += az0; h0.w += aw0;
    *hp0 = h0;
    if (r1 < N) {
        float4* hp1 = (float4*)(H + (size_t)r1 * 32 + lane * 4);
        float4 h1 = *hp1;
        h1.x += ax1; h1.y += ay1; h1.z += az1; h1.w += aw1;
        *hp1 = h1;
    }
}

// C=10: 2 rows per thread, lanes 0..4 handle float2 each
__global__ __launch_bounds__(256) void gather10(
    const int* __restrict__ rowptr, const int2* __restrict__ ecv,
    const float* __restrict__ Z, float* __restrict__ H, int N)
{
    int tid = blockIdx.x * 256 + threadIdx.x;
    int pr = tid >> 3, lane = tid & 7;
    int r0 = pr * 2, r1 = r0 + 1;
    if (r0 >= N || lane >= 5) return;
    int s0 = rowptr[r0], e0 = rowptr[r0 + 1];
    int s1 = 0, e1 = 0;
    if (r1 < N) { s1 = rowptr[r1]; e1 = rowptr[r1 + 1]; }
    float ax0 = 0.f, ay0 = 0.f, ax1 = 0.f, ay1 = 0.f;
    int i0 = s0, i1 = s1;
    while (i0 < e0 && i1 < e1) {
        int2 c0 = ecv[i0]; int2 c1 = ecv[i1];
        float2 z0 = *(const float2*)(Z + (size_t)c0.x * 32 + lane * 2);
        float2 z1 = *(const float2*)(Z + (size_t)c1.x * 32 + lane * 2);
        float v0 = __int_as_float(c0.y), v1 = __int_as_float(c1.y);
        ax0 = fmaf(v0, z0.x, ax0); ay0 = fmaf(v0, z0.y, ay0);
        ax1 = fmaf(v1, z1.x, ax1); ay1 = fmaf(v1, z1.y, ay1);
        i0++; i1++;
    }
    for (; i0 < e0; i0++) {
        int2 c0 = ecv[i0];
        float2 z0 = *(const float2*)(Z + (size_t)c0.x * 32 + lane * 2);
        float v0 = __int_as_float(c0.y);
        ax0 = fmaf(v0, z0.x, ax0); ay0 = fmaf(v0, z0.y, ay0);
    }
    for (; i1 < e1; i1++) {
        int2 c1 = ecv[i1];
        float2 z1 = *(const float2*)(Z + (size_t)c1.x * 32 + lane * 2);
        float v1 = __int_as_float(c1.y);
        ax1 = fmaf(v1, z1.x, ax1); ay1 = fmaf(v1, z1.y, ay1);
    }
    float* hp0 = H + (size_t)r0 * 32 + lane * 2;
    hp0[0] += ax0; hp0[1] += ay0;
    if (r1 < N) {
        float* hp1 = H + (size_t)r1 * 32 + lane * 2;
        hp1[0] += ax1; hp1[1] += ay1;
    }
}

// one block per graph; batch is sorted -> binary search node range, no atomics
__global__ __launch_bounds__(256) void pool_graph(
    const float* __restrict__ H, const int* __restrict__ batch,
    float* __restrict__ pool, int N, int dimoff)
{
    int g = blockIdx.x;
    int lo = 0, hi = N;
    while (lo < hi) { int mid = (lo + hi) >> 1; if (batch[mid] < g) lo = mid + 1; else hi = mid; }
    int start = lo;
    lo = start; hi = N;
    while (lo < hi) { int mid = (lo + hi) >> 1; if (batch[mid] < g + 1) lo = mid + 1; else hi = mid; }
    int end = lo;
    int t = threadIdx.x, f = t & 15, chain = t >> 4;
    __shared__ float sd[256];
    float acc = 0.f;
    if (f < 10) {
        for (int i = start + chain; i < end; i += 16) acc += H[(size_t)i * 32 + f];
    }
    sd[t] = acc; __syncthreads();
    if (chain == 0 && f < 10) {
        float s = 0.f;
#pragma unroll
        for (int k = 0; k < 16; k++) s += sd[k * 16 + f];
        int c = end - start;
        float inv = 1.f / (float)(c > 1 ? c : 1);
        pool[(size_t)g * 30 + dimoff + f] = s * inv;
    }
}

__global__ __launch_bounds__(256) void final_kernel(
    const float* __restrict__ pool, const float* __restrict__ Wf,
    const float* __restrict__ bfv, float* __restrict__ out, int G)
{
    int g = blockIdx.x * 256 + threadIdx.x;
    if (g >= G) return;
    float m[30];
#pragma unroll
    for (int j = 0; j < 30; j++) m[j] = pool[(size_t)g * 30 + j];
    float lg[10];
#pragma unroll
    for (int o = 0; o < 10; o++) {
        float a = bfv[o];
#pragma unroll
        for (int j = 0; j < 30; j++) a = fmaf(m[j], Wf[j * 10 + o], a);
        lg[o] = a;
    }
    float mx = lg[0];
#pragma unroll
    for (int o = 1; o < 10; o++) mx = fmaxf(mx, lg[o]);
    float s = 0.f;
#pragma unroll
    for (int o = 0; o < 10; o++) { lg[o] = __expf(lg[o] - mx); s += lg[o]; }
    float invs = 1.f / s;
#pragma unroll
    for (int o = 0; o < 10; o++) out[(size_t)g * 10 + o] = lg[o] * invs;
}

extern "C" void kernel_launch(void* const* d_in, const int* in_sizes, int n_in,
                              void* d_out, int out_size, void* d_ws, size_t ws_size,
                              hipStream_t stream)
{
    (void)n_in; (void)ws_size;
    const float* x[3]    = {(const float*)d_in[0], (const float*)d_in[1], (const float*)d_in[2]};
    const float* vals[3] = {(const float*)d_in[3], (const float*)d_in[4], (const float*)d_in[5]};
    const int* rows[3]   = {(const int*)d_in[6], (const int*)d_in[8], (const int*)d_in[10]};
    const int* cols[3]   = {(const int*)d_in[7], (const int*)d_in[9], (const int*)d_in[11]};
    const int* batch[3]  = {(const int*)d_in[12], (const int*)d_in[13], (const int*)d_in[14]};
    const float* W1[3] = {(const float*)d_in[16], (const float*)d_in[22], (const float*)d_in[28]};
    const float* b1[3] = {(const float*)d_in[17], (const float*)d_in[23], (const float*)d_in[29]};
    const float* W2[3] = {(const float*)d_in[18], (const float*)d_in[24], (const float*)d_in[30]};
    const float* b2[3] = {(const float*)d_in[19], (const float*)d_in[25], (const float*)d_in[31]};
    const float* W3[3] = {(const float*)d_in[20], (const float*)d_in[26], (const float*)d_in[32]};
    const float* b3[3] = {(const float*)d_in[21], (const float*)d_in[27], (const float*)d_in[33]};
    const float* Wf  = (const float*)d_in[34];
    const float* bfv = (const float*)d_in[35];
    float* out = (float*)d_out;

    int N[3] = {in_sizes[0] / 32, in_sizes[1] / 32, in_sizes[2] / 32};
    int E[3] = {in_sizes[3], in_sizes[4], in_sizes[5]};
    int G = out_size / 10;
    int maxN = N[0]; if (N[1] > maxN) maxN = N[1]; if (N[2] > maxN) maxN = N[2];
    int maxE = E[0]; if (E[1] > maxE) maxE = E[1]; if (E[2] > maxE) maxE = E[2];
    int maxNBm = cdiv(maxN, 1 << MSHIFT);

    float* bufA   = (float*)d_ws;                       // layers; aliases stg1 during build
    float* bufZ   = bufA + (size_t)maxN * 32;           // layers; aliases stgm during build
    int2*  stg1   = (int2*)bufA;                        // build-phase only
    int2*  stgm   = (int2*)bufZ;                        // build-phase only
    float* pool   = bufZ + (size_t)maxN * 32;
    int2*  ecv    = (int2*)(pool + (size_t)G * 30 + 2); // +2 for int2 alignment
    int*   rowptr = (int*)(ecv + maxE);
    int*   cnt    = rowptr + (maxN + 1);
    int*   ccnt   = cnt + maxN;
    int*   cbase  = ccnt + 64;
    int*   cfront = cbase + 66;
    int*   mfront = cfront + 64;
    int*   bsums  = mfront + (maxNBm + 1);

    for (int d = 0; d < 3; d++) {
        int n = N[d], e = E[d];
        int nb = cdiv(n, SCAN_TILE);
        int NBc = cdiv(n, 1 << CSHIFT);
        int NBm = cdiv(n, 1 << MSHIFT);
        int ntile = cdiv(e, TILE_E);

        // --- rowptr ---
        zero_i32<<<cdiv(n, 256), 256, 0, stream>>>(cnt, n);
        hist_rows<<<cdiv(e, 256), 256, 0, stream>>>(rows[d], cnt, e);
        scan1<<<nb, 256, 0, stream>>>(cnt, bsums, n);
        scan2<<<1, 64, 0, stream>>>(bsums, nb);
        scan3<<<nb, 256, 0, stream>>>(cnt, rowptr, bsums, n, e);
        // --- coarse split (dense chunks) -> mid split (dense chunks) -> in-block CSR sort ---
        zero_i32<<<1, 256, 0, stream>>>(ccnt, 64);
        hist_coarse<<<ntile, 256, 0, stream>>>(rows[d], ccnt, e);
        scan_coarse<<<1, 64, 0, stream>>>(ccnt, cbase, cfront, NBc, e);
        split_coarse<<<ntile, 256, 0, stream>>>(rows[d], cols[d], vals[d], cfront, stg1, e);
        init_mfront<<<cdiv(NBm, 256), 256, 0, stream>>>(rowptr, mfront, NBm);
        split_mid<<<ntile, 256, 0, stream>>>(stg1, cbase, mfront, stgm, e, NBc);
        csr_sort<<<NBm, 256, 0, stream>>>(stgm, rowptr, ecv, n);

        // --- 3 layers, conflict-free CSR gathers (dual-chain) ---
        dense_kernel<32, false><<<cdiv(n, 256), 256, 0, stream>>>(x[d], W1[d], b1[d], bufA, bufZ, n);
        gather32<<<cdiv((long long)cdiv(n, 2) * 8, 256), 256, 0, stream>>>(rowptr, ecv, bufZ, bufA, n);
        dense_kernel<32, true><<<cdiv(n, 256), 256, 0, stream>>>(bufA, W2[d], b2[d], bufA, bufZ, n);
        gather32<<<cdiv((long long)cdiv(n, 2) * 8, 256), 256, 0, stream>>>(rowptr, ecv, bufZ, bufA, n);
        dense_kernel<10, true><<<cdiv(n, 256), 256, 0, stream>>>(bufA, W3[d], b3[d], bufA, bufZ, n);
        gather10<<<cdiv((long long)cdiv(n, 2) * 8, 256), 256, 0, stream>>>(rowptr, ecv, bufZ, bufA, n);
        pool_graph<<<G, 256, 0, stream>>>(bufA, batch[d], pool, n, d * 10);
    }
    final_kernel<<<cdiv(G, 256), 256, 0, stream>>>(pool, Wf, bfv, out, G);
}

// Round 7
// 1501.304 us; speedup vs baseline: 2.6750x; 1.2238x over previous
//
#include <hip/hip_runtime.h>

#define NEG_SLOPE 0.01f
#define CSHIFT 13               // 8192 rows per coarse bucket (<=49 coarse for N<=400k)
#define MSHIFT 7                // 128 rows per mid bucket
#define MPC (1 << (CSHIFT - MSHIFT))   // 64 mids per coarse
#define MWIN 192                // window of mid-counters per split tile (straddle<=2 coarse)
#define CAP 4096                // max edges per mid bucket in csr_sort LDS
#define TILE_E 2048             // edges per split tile

static inline int cdiv(long long a, long long b) { return (int)((a + b - 1) / b); }

__global__ __launch_bounds__(256) void zero_i32(int* __restrict__ p, int n) {
    int i = blockIdx.x * 256 + threadIdx.x;
    if (i < n) p[i] = 0;
}

// ---- coarse histogram: LDS counters, one merge atomic per (block,bucket) ----
__global__ __launch_bounds__(256) void hist_coarse(const int* __restrict__ rows, int* __restrict__ ccnt, int E) {
    __shared__ int cnt[64];
    int t = threadIdx.x;
    if (t < 64) cnt[t] = 0;
    __syncthreads();
    int base = blockIdx.x * TILE_E;
#pragma unroll
    for (int k = 0; k < TILE_E / 256; k++) {
        int e = base + k * 256 + t;
        if (e < E) atomicAdd(&cnt[rows[e] >> CSHIFT], 1);
    }
    __syncthreads();
    if (t < 64 && cnt[t] > 0) atomicAdd(&ccnt[t], cnt[t]);
}

__global__ void scan_coarse(const int* __restrict__ ccnt, int* __restrict__ cbase,
                            int* __restrict__ cfront, int NBc, int E) {
    if (threadIdx.x == 0 && blockIdx.x == 0) {
        int run = 0;
        for (int b = 0; b < NBc; b++) { cbase[b] = run; cfront[b] = run; run += ccnt[b]; }
        cbase[NBc] = E;
    }
}

// ---- pass A: LDS multisplit into coarse buckets; dense chunk writes ----
// record: ( (row & 8191) << 19 | col , val )   [13+19 = 32 bits exactly, col < 2^19]
__global__ __launch_bounds__(256) void split_coarse(
    const int* __restrict__ rows, const int* __restrict__ cols, const float* __restrict__ vals,
    int* __restrict__ cfront, int2* __restrict__ stg1, int E)
{
    __shared__ int cnt[64], gb[64];
    int t = threadIdx.x;
    if (t < 64) cnt[t] = 0;
    __syncthreads();
    int base = blockIdx.x * TILE_E;
    int myb[8], myrank[8]; int2 mycv[8];
#pragma unroll
    for (int k = 0; k < 8; k++) {
        int e = base + k * 256 + t;
        myb[k] = -1;
        if (e < E) {
            int r = rows[e];
            int b = r >> CSHIFT;
            mycv[k] = make_int2((int)(((unsigned)(r & ((1 << CSHIFT) - 1)) << 19) | (unsigned)cols[e]),
                                __float_as_int(vals[e]));
            myb[k] = b;
            myrank[k] = atomicAdd(&cnt[b], 1);
        }
    }
    __syncthreads();
    if (t < 64 && cnt[t] > 0) gb[t] = atomicAdd(&cfront[t], cnt[t]);
    __syncthreads();
#pragma unroll
    for (int k = 0; k < 8; k++)
        if (myb[k] >= 0) stg1[gb[myb[k]] + myrank[k]] = mycv[k];
}

// ---- mid histogram from coarse-sorted staging (windowed LDS counters) ----
__global__ __launch_bounds__(256) void hist_mid(
    const int2* __restrict__ stg1, const int* __restrict__ cbase_g,
    int* __restrict__ mcnt, int E, int NBc)
{
    __shared__ int cb[66];
    __shared__ int wc[MWIN];
    int t = threadIdx.x;
    for (int i = t; i <= NBc; i += 256) cb[i] = cbase_g[i];
    for (int i = t; i < MWIN; i += 256) wc[i] = 0;
    __syncthreads();
    int base = blockIdx.x * TILE_E;
    int lo = 0, hi = NBc - 1;
    while (lo < hi) { int m = (lo + hi + 1) >> 1; if (cb[m] <= base) lo = m; else hi = m - 1; }
    int winm = lo * MPC;
#pragma unroll
    for (int k = 0; k < 8; k++) {
        int e = base + k * 256 + t;
        if (e < E) {
            int b = lo;
            while (cb[b + 1] <= e) b++;
            int m = b * MPC + (int)(((unsigned)stg1[e].x >> 19) >> MSHIFT);
            int lf = m - winm;
            if (lf >= 0 && lf < MWIN) atomicAdd(&wc[lf], 1);
            else atomicAdd(&mcnt[m], 1);    // rare fallback
        }
    }
    __syncthreads();
    for (int i = t; i < MWIN; i += 256)
        if (wc[i] > 0) atomicAdd(&mcnt[winm + i], wc[i]);
}

// ---- single-block scan over mid buckets (NBm <= 3125) -> mbase, mfront ----
__global__ __launch_bounds__(256) void scan_mid(
    const int* __restrict__ mcnt, int* __restrict__ mbase,
    int* __restrict__ mfront, int NBm, int E)
{
    __shared__ int sd[256];
    __shared__ int carry;
    int t = threadIdx.x;
    if (t == 0) carry = 0;
    __syncthreads();
    for (int base = 0; base < NBm; base += 256) {
        int v = (base + t < NBm) ? mcnt[base + t] : 0;
        sd[t] = v;
        __syncthreads();
        for (int off = 1; off < 256; off <<= 1) {
            int x = (t >= off) ? sd[t - off] : 0;
            __syncthreads();
            sd[t] += x;
            __syncthreads();
        }
        int incl = sd[t] + carry;
        int excl = incl - v;
        if (base + t < NBm) { mbase[base + t] = excl; mfront[base + t] = excl; }
        __syncthreads();
        if (t == 255) carry = incl;
        __syncthreads();
    }
    if (t == 0) mbase[NBm] = E;
}

// ---- pass B: coarse-sorted staging -> mid (128-row) buckets; windowed LDS ranking ----
__global__ __launch_bounds__(256) void split_mid(
    const int2* __restrict__ stg1, const int* __restrict__ cbase_g,
    int* __restrict__ mfront, int2* __restrict__ stgm, int E, int NBc)
{
    __shared__ int cb[66];
    __shared__ int wc[MWIN], wg[MWIN];
    int t = threadIdx.x;
    for (int i = t; i <= NBc; i += 256) cb[i] = cbase_g[i];
    for (int i = t; i < MWIN; i += 256) wc[i] = 0;
    __syncthreads();
    int base = blockIdx.x * TILE_E;
    int lo = 0, hi = NBc - 1;
    while (lo < hi) { int m = (lo + hi + 1) >> 1; if (cb[m] <= base) lo = m; else hi = m - 1; }
    int winm = lo * MPC;
    int mylf[8], myrank[8]; int2 myp[8];
#pragma unroll
    for (int k = 0; k < 8; k++) {
        int e = base + k * 256 + t;
        mylf[k] = -1;
        if (e < E) {
            int b = lo;
            while (cb[b + 1] <= e) b++;
            int2 cv = stg1[e];
            int m = (b << (CSHIFT - MSHIFT)) + (int)(((unsigned)cv.x >> 19) >> MSHIFT);
            int lf = m - winm;
            if (lf >= 0 && lf < MWIN) { mylf[k] = lf; myrank[k] = atomicAdd(&wc[lf], 1); myp[k] = cv; }
            else stgm[atomicAdd(&mfront[m], 1)] = cv;   // rare fallback
        }
    }
    __syncthreads();
    for (int i = t; i < MWIN; i += 256)
        if (wc[i] > 0) wg[i] = atomicAdd(&mfront[winm + i], wc[i]);
    __syncthreads();
#pragma unroll
    for (int k = 0; k < 8; k++)
        if (mylf[k] >= 0) stgm[wg[mylf[k]] + myrank[k]] = myp[k];
}

// ---- pass C: one block per mid bucket; computes its own row counts + rowptr,
//      LDS counting sort to exact CSR; all global writes sequential/dense ----
__global__ __launch_bounds__(256) void csr_sort(
    const int2* __restrict__ stgm, const int* __restrict__ mbase,
    int* __restrict__ rowptr, int2* __restrict__ ecv, int N)
{
    __shared__ int2 buf[CAP];
    __shared__ int cnt[128], sc[128], front[128];
    int mb = blockIdx.x, t = threadIdx.x;
    int row0 = mb << MSHIFT;
    int nrows = N - row0; if (nrows > 128) nrows = 128;
    int s = mbase[mb], eend = mbase[mb + 1];
    if (t < 128) cnt[t] = 0;
    __syncthreads();
    // pass 1: count rows (contiguous L2-resident reads)
    for (int i = s + t; i < eend; i += 256)
        atomicAdd(&cnt[((unsigned)stgm[i].x >> 19) & 127], 1);
    __syncthreads();
    // exclusive scan of 128 counters
    if (t < 128) sc[t] = cnt[t];
    __syncthreads();
    for (int off = 1; off < 128; off <<= 1) {
        int x = (t >= off && t < 128) ? sc[t - off] : 0;
        __syncthreads();
        if (t < 128) sc[t] += x;
        __syncthreads();
    }
    if (t < 128) front[t] = sc[t] - cnt[t];
    if (t < nrows) rowptr[row0 + t] = s + sc[t] - cnt[t];
    if (t == 0 && row0 + nrows == N) rowptr[N] = eend;
    __syncthreads();
    // pass 2: place into LDS at exact local CSR position
    for (int i = s + t; i < eend; i += 256) {
        int2 cv = stgm[i];
        unsigned p = (unsigned)cv.x;
        int rl = ((int)(p >> 19)) & 127;
        int2 rec = make_int2((int)(p & 0x7FFFFu), cv.y);
        int l = atomicAdd(&front[rl], 1);
        if (l < CAP) buf[l] = rec;
        else ecv[s + l] = rec;               // overflow fallback (statistically never)
    }
    __syncthreads();
    int total = eend - s; if (total > CAP) total = CAP;
    for (int l = t; l < total; l += 256) ecv[s + l] = buf[l];
}

// H[n,:] = act(in[n,:]) @ W[0:32,:] + b ;  Z[n,:] = act(in[n,:]) @ W[32:64,:]
template<int COUT, bool LRELU>
__global__ __launch_bounds__(256) void dense_kernel(
    const float* in, const float* __restrict__ W,
    const float* __restrict__ b, float* H,
    float* __restrict__ Z, int N)
{
    int n = blockIdx.x * 256 + threadIdx.x;
    if (n >= N) return;
    const float* row = in + (size_t)n * 32;
    float xv[32];
#pragma unroll
    for (int f = 0; f < 32; f += 4) {
        float4 v = *(const float4*)(row + f);
        xv[f] = v.x; xv[f + 1] = v.y; xv[f + 2] = v.z; xv[f + 3] = v.w;
    }
    if (LRELU) {
#pragma unroll
        for (int f = 0; f < 32; f++) xv[f] = xv[f] > 0.f ? xv[f] : NEG_SLOPE * xv[f];
    }
    float acct[COUT], accb[COUT];
#pragma unroll
    for (int c = 0; c < COUT; c++) { acct[c] = b[c]; accb[c] = 0.f; }
#pragma unroll 4
    for (int f = 0; f < 32; f++) {
        float xf = xv[f];
#pragma unroll
        for (int c = 0; c < COUT; c++) {
            acct[c] = fmaf(xf, W[f * COUT + c], acct[c]);
            accb[c] = fmaf(xf, W[(32 + f) * COUT + c], accb[c]);
        }
    }
    float* hrow = H + (size_t)n * 32;
    float* zrow = Z + (size_t)n * 32;
#pragma unroll
    for (int c = 0; c < COUT; c++) { hrow[c] = acct[c]; zrow[c] = accb[c]; }
}

// CSR gather, 2 interleaved row-chains per thread (C=32, 8 lanes x float4)
__global__ __launch_bounds__(256) void gather32(
    const int* __restrict__ rowptr, const int2* __restrict__ ecv,
    const float* __restrict__ Z, float* __restrict__ H, int N)
{
    int tid = blockIdx.x * 256 + threadIdx.x;
    int pr = tid >> 3, lane = tid & 7;
    int r0 = pr * 2, r1 = r0 + 1;
    if (r0 >= N) return;
    int s0 = rowptr[r0], e0 = rowptr[r0 + 1];
    int s1 = 0, e1 = 0;
    if (r1 < N) { s1 = rowptr[r1]; e1 = rowptr[r1 + 1]; }
    float ax0 = 0.f, ay0 = 0.f, az0 = 0.f, aw0 = 0.f;
    float ax1 = 0.f, ay1 = 0.f, az1 = 0.f, aw1 = 0.f;
    int i0 = s0, i1 = s1;
    while (i0 < e0 && i1 < e1) {
        int2 c0 = ecv[i0]; int2 c1 = ecv[i1];
        float4 z0 = *(const float4*)(Z + (size_t)c0.x * 32 + lane * 4);
        float4 z1 = *(const float4*)(Z + (size_t)c1.x * 32 + lane * 4);
        float v0 = __int_as_float(c0.y), v1 = __int_as_float(c1.y);
        ax0 = fmaf(v0, z0.x, ax0); ay0 = fmaf(v0, z0.y, ay0);
        az0 = fmaf(v0, z0.z, az0); aw0 = fmaf(v0, z0.w, aw0);
        ax1 = fmaf(v1, z1.x, ax1); ay1 = fmaf(v1, z1.y, ay1);
        az1 = fmaf(v1, z1.z, az1); aw1 = fmaf(v1, z1.w, aw1);
        i0++; i1++;
    }
    for (; i0 < e0; i0++) {
        int2 c0 = ecv[i0];
        float4 z0 = *(const float4*)(Z + (size_t)c0.x * 32 + lane * 4);
        float v0 = __int_as_float(c0.y);
        ax0 = fmaf(v0, z0.x, ax0); ay0 = fmaf(v0, z0.y, ay0);
        az0 = fmaf(v0, z0.z, az0); aw0 = fmaf(v0, z0.w, aw0);
    }
    for (; i1 < e1; i1++) {
        int2 c1 = ecv[i1];
        float4 z1 = *(const float4*)(Z + (size_t)c1.x * 32 + lane * 4);
        float v1 = __int_as_float(c1.y);
        ax1 = fmaf(v1, z1.x, ax1); ay1 = fmaf(v1, z1.y, ay1);
        az1 = fmaf(v1, z1.z, az1); aw1 = fmaf(v1, z1.w, aw1);
    }
    float4* hp0 = (float4*)(H + (size_t)r0 * 32 + lane * 4);
    float4 h0 = *hp0;
    h0.x += ax0; h0.y += ay0; h0.z += az0; h0.w += aw0;
    *hp0 = h0;
    if (r1 < N) {
        float4* hp1 = (float4*)(H + (size_t)r1 * 32 + lane * 4);
        float4 h1 = *hp1;
        h1.x += ax1; h1.y += ay1; h1.z += az1; h1.w += aw1;
        *hp1 = h1;
    }
}

// C=10: 2 rows per thread, lanes 0..4 handle float2 each
__global__ __launch_bounds__(256) void gather10(
    const int* __restrict__ rowptr, const int2* __restrict__ ecv,
    const float* __restrict__ Z, float* __restrict__ H, int N)
{
    int tid = blockIdx.x * 256 + threadIdx.x;
    int pr = tid >> 3, lane = tid & 7;
    int r0 = pr * 2, r1 = r0 + 1;
    if (r0 >= N || lane >= 5) return;
    int s0 = rowptr[r0], e0 = rowptr[r0 + 1];
    int s1 = 0, e1 = 0;
    if (r1 < N) { s1 = rowptr[r1]; e1 = rowptr[r1 + 1]; }
    float ax0 = 0.f, ay0 = 0.f, ax1 = 0.f, ay1 = 0.f;
    int i0 = s0, i1 = s1;
    while (i0 < e0 && i1 < e1) {
        int2 c0 = ecv[i0]; int2 c1 = ecv[i1];
        float2 z0 = *(const float2*)(Z + (size_t)c0.x * 32 + lane * 2);
        float2 z1 = *(const float2*)(Z + (size_t)c1.x * 32 + lane * 2);
        float v0 = __int_as_float(c0.y), v1 = __int_as_float(c1.y);
        ax0 = fmaf(v0, z0.x, ax0); ay0 = fmaf(v0, z0.y, ay0);
        ax1 = fmaf(v1, z1.x, ax1); ay1 = fmaf(v1, z1.y, ay1);
        i0++; i1++;
    }
    for (; i0 < e0; i0++) {
        int2 c0 = ecv[i0];
        float2 z0 = *(const float2*)(Z + (size_t)c0.x * 32 + lane * 2);
        float v0 = __int_as_float(c0.y);
        ax0 = fmaf(v0, z0.x, ax0); ay0 = fmaf(v0, z0.y, ay0);
    }
    for (; i1 < e1; i1++) {
        int2 c1 = ecv[i1];
        float2 z1 = *(const float2*)(Z + (size_t)c1.x * 32 + lane * 2);
        float v1 = __int_as_float(c1.y);
        ax1 = fmaf(v1, z1.x, ax1); ay1 = fmaf(v1, z1.y, ay1);
    }
    float* hp0 = H + (size_t)r0 * 32 + lane * 2;
    hp0[0] += ax0; hp0[1] += ay0;
    if (r1 < N) {
        float* hp1 = H + (size_t)r1 * 32 + lane * 2;
        hp1[0] += ax1; hp1[1] += ay1;
    }
}

// one block per graph; batch is sorted -> binary search node range, no atomics
__global__ __launch_bounds__(256) void pool_graph(
    const float* __restrict__ H, const int* __restrict__ batch,
    float* __restrict__ pool, int N, int dimoff)
{
    int g = blockIdx.x;
    int lo = 0, hi = N;
    while (lo < hi) { int mid = (lo + hi) >> 1; if (batch[mid] < g) lo = mid + 1; else hi = mid; }
    int start = lo;
    lo = start; hi = N;
    while (lo < hi) { int mid = (lo + hi) >> 1; if (batch[mid] < g + 1) lo = mid + 1; else hi = mid; }
    int end = lo;
    int t = threadIdx.x, f = t & 15, chain = t >> 4;
    __shared__ float sd[256];
    float acc = 0.f;
    if (f < 10) {
        for (int i = start + chain; i < end; i += 16) acc += H[(size_t)i * 32 + f];
    }
    sd[t] = acc; __syncthreads();
    if (chain == 0 && f < 10) {
        float s = 0.f;
#pragma unroll
        for (int k = 0; k < 16; k++) s += sd[k * 16 + f];
        int c = end - start;
        float inv = 1.f / (float)(c > 1 ? c : 1);
        pool[(size_t)g * 30 + dimoff + f] = s * inv;
    }
}

__global__ __launch_bounds__(256) void final_kernel(
    const float* __restrict__ pool, const float* __restrict__ Wf,
    const float* __restrict__ bfv, float* __restrict__ out, int G)
{
    int g = blockIdx.x * 256 + threadIdx.x;
    if (g >= G) return;
    float m[30];
#pragma unroll
    for (int j = 0; j < 30; j++) m[j] = pool[(size_t)g * 30 + j];
    float lg[10];
#pragma unroll
    for (int o = 0; o < 10; o++) {
        float a = bfv[o];
#pragma unroll
        for (int j = 0; j < 30; j++) a = fmaf(m[j], Wf[j * 10 + o], a);
        lg[o] = a;
    }
    float mx = lg[0];
#pragma unroll
    for (int o = 1; o < 10; o++) mx = fmaxf(mx, lg[o]);
    float s = 0.f;
#pragma unroll
    for (int o = 0; o < 10; o++) { lg[o] = __expf(lg[o] - mx); s += lg[o]; }
    float invs = 1.f / s;
#pragma unroll
    for (int o = 0; o < 10; o++) out[(size_t)g * 10 + o] = lg[o] * invs;
}

extern "C" void kernel_launch(void* const* d_in, const int* in_sizes, int n_in,
                              void* d_out, int out_size, void* d_ws, size_t ws_size,
                              hipStream_t stream)
{
    (void)n_in; (void)ws_size;
    const float* x[3]    = {(const float*)d_in[0], (const float*)d_in[1], (const float*)d_in[2]};
    const float* vals[3] = {(const float*)d_in[3], (const float*)d_in[4], (const float*)d_in[5]};
    const int* rows[3]   = {(const int*)d_in[6], (const int*)d_in[8], (const int*)d_in[10]};
    const int* cols[3]   = {(const int*)d_in[7], (const int*)d_in[9], (const int*)d_in[11]};
    const int* batch[3]  = {(const int*)d_in[12], (const int*)d_in[13], (const int*)d_in[14]};
    const float* W1[3] = {(const float*)d_in[16], (const float*)d_in[22], (const float*)d_in[28]};
    const float* b1[3] = {(const float*)d_in[17], (const float*)d_in[23], (const float*)d_in[29]};
    const float* W2[3] = {(const float*)d_in[18], (const float*)d_in[24], (const float*)d_in[30]};
    const float* b2[3] = {(const float*)d_in[19], (const float*)d_in[25], (const float*)d_in[31]};
    const float* W3[3] = {(const float*)d_in[20], (const float*)d_in[26], (const float*)d_in[32]};
    const float* b3[3] = {(const float*)d_in[21], (const float*)d_in[27], (const float*)d_in[33]};
    const float* Wf  = (const float*)d_in[34];
    const float* bfv = (const float*)d_in[35];
    float* out = (float*)d_out;

    int N[3] = {in_sizes[0] / 32, in_sizes[1] / 32, in_sizes[2] / 32};
    int E[3] = {in_sizes[3], in_sizes[4], in_sizes[5]};
    int G = out_size / 10;
    int maxN = N[0]; if (N[1] > maxN) maxN = N[1]; if (N[2] > maxN) maxN = N[2];
    int maxE = E[0]; if (E[1] > maxE) maxE = E[1]; if (E[2] > maxE) maxE = E[2];
    int maxNBm = cdiv(maxN, 1 << MSHIFT);

    float* bufA   = (float*)d_ws;                       // layers; aliases stg1 during build
    float* bufZ   = bufA + (size_t)maxN * 32;           // layers; aliases stgm during build
    int2*  stg1   = (int2*)bufA;                        // build-phase only
    int2*  stgm   = (int2*)bufZ;                        // build-phase only
    float* pool   = bufZ + (size_t)maxN * 32;
    int2*  ecv    = (int2*)(pool + (size_t)G * 30 + 2); // +2 for int2 alignment
    int*   rowptr = (int*)(ecv + maxE);
    int*   mcnt   = rowptr + (maxN + 1);
    int*   mbase  = mcnt + maxNBm;
    int*   mfront = mbase + (maxNBm + 1);
    int*   ccnt   = mfront + maxNBm;
    int*   cbase  = ccnt + 64;
    int*   cfront = cbase + 66;

    for (int d = 0; d < 3; d++) {
        int n = N[d], e = E[d];
        int NBc = cdiv(n, 1 << CSHIFT);
        int NBm = cdiv(n, 1 << MSHIFT);
        int ntile = cdiv(e, TILE_E);

        // --- coarse split -> mid split -> in-block CSR sort (writes rowptr itself) ---
        zero_i32<<<1, 256, 0, stream>>>(ccnt, 64);
        hist_coarse<<<ntile, 256, 0, stream>>>(rows[d], ccnt, e);
        scan_coarse<<<1, 64, 0, stream>>>(ccnt, cbase, cfront, NBc, e);
        split_coarse<<<ntile, 256, 0, stream>>>(rows[d], cols[d], vals[d], cfront, stg1, e);
        zero_i32<<<cdiv(NBm, 256), 256, 0, stream>>>(mcnt, NBm);
        hist_mid<<<ntile, 256, 0, stream>>>(stg1, cbase, mcnt, e, NBc);
        scan_mid<<<1, 256, 0, stream>>>(mcnt, mbase, mfront, NBm, e);
        split_mid<<<ntile, 256, 0, stream>>>(stg1, cbase, mfront, stgm, e, NBc);
        csr_sort<<<NBm, 256, 0, stream>>>(stgm, mbase, rowptr, ecv, n);

        // --- 3 layers, conflict-free CSR gathers (dual-chain) ---
        dense_kernel<32, false><<<cdiv(n, 256), 256, 0, stream>>>(x[d], W1[d], b1[d], bufA, bufZ, n);
        gather32<<<cdiv((long long)cdiv(n, 2) * 8, 256), 256, 0, stream>>>(rowptr, ecv, bufZ, bufA, n);
        dense_kernel<32, true><<<cdiv(n, 256), 256, 0, stream>>>(bufA, W2[d], b2[d], bufA, bufZ, n);
        gather32<<<cdiv((long long)cdiv(n, 2) * 8, 256), 256, 0, stream>>>(rowptr, ecv, bufZ, bufA, n);
        dense_kernel<10, true><<<cdiv(n, 256), 256, 0, stream>>>(bufA, W3[d], b3[d], bufA, bufZ, n);
        gather10<<<cdiv((long long)cdiv(n, 2) * 8, 256), 256, 0, stream>>>(rowptr, ecv, bufZ, bufA, n);
        pool_graph<<<G, 256, 0, stream>>>(bufA, batch[d], pool, n, d * 10);
    }
    final_kernel<<<cdiv(G, 256), 256, 0, stream>>>(pool, Wf, bfv, out, G);
}